// Round 9
// baseline (136.734 us; speedup 1.0000x reference)
//
#include <hip/hip_runtime.h>
#include <float.h>

// QKV attention, qkv [2,3072,2048] f32, mask [2,1,2048] i32, out [2,1024,2048] f32.
// R9 = R8 + two exposed-latency cuts (TLP measured-free across R2-R8; per-wave
// serial stalls dominate):
//  (a) V prefetched 1-deep alongside K (static A/B pairs): V was issued at
//      step start and consumed ~250cy later -- an L2 hit barely/not covered.
//  (b) mask moved OFF the critical path: S-MFMA C-init was an LDS bias read
//      (~120cy) gating the first MFMA. Now zero-C-init + post-exp flag
//      multiply (p = e * flag, flags 1.0/0.0 read AFTER MFMA issue, covered
//      by the exp chain).
// launch_bounds (256,3): ~150 live regs must not spill (R3 lesson).
// Math: 32x32x16 MFMA, swapped QK (lane-local P rows), in-register softmax
// via v_cvt_pk_bf16_f32 + v_permlane32_swap_b32, fixed-max exp2.

typedef __attribute__((ext_vector_type(8))) short bf16x8;
typedef __attribute__((ext_vector_type(4))) float f32x4;
typedef __attribute__((ext_vector_type(16))) float f32x16;

#define TSEQ 2048
#define QT_OFF 0L
#define KF_OFF 4194304L
#define VF_OFF 8388608L

#if __has_builtin(__builtin_amdgcn_exp2f)
#define EXPFN(x) __builtin_amdgcn_exp2f(x)
#define SM_SCALE (0.125f * 1.44269504088896f)
#else
#define EXPFN(x) __expf(x)
#define SM_SCALE 0.125f
#endif

__device__ inline short f2bf(float x) {
    union { float f; unsigned u; } un; un.f = x;
    unsigned r = un.u + 0x7fffu + ((un.u >> 16) & 1u);  // RNE
    return (short)(r >> 16);
}

// pack two f32 -> [bf16(lo) | bf16(hi)<<16], single HW op
__device__ inline unsigned cvtpk(float lo, float hi) {
    unsigned r;
    asm("v_cvt_pk_bf16_f32 %0, %1, %2" : "=v"(r) : "v"(lo), "v"(hi));
    return r;
}

// swap a's lanes 32-63 with b's lanes 0-31 (register-only cross-half exchange)
__device__ inline void pl32swap(unsigned &a, unsigned &b) {
    asm volatile("v_permlane32_swap_b32 %0, %1" : "+v"(a), "+v"(b));
}

// ---------------- pre-pass: convert + reorder ----------------
// 3072 blocks: tpe = job>>10 (0=Q,1=K,2=V), 1024 each: bh = 0..31, tt = 0..31.
// All types share one coalesced 64x64 f32 tile load into padded LDS.
__global__ __launch_bounds__(256) void prep_kernel(
    const float* __restrict__ qkv, short* __restrict__ ws)
{
    const int tid = threadIdx.x;
    const int job = blockIdx.x;
    const int tpe  = job >> 10;          // 0=Q 1=K 2=V
    const int rest = job & 1023;
    const int bh = rest & 31, tt = rest >> 5;
    const int b = bh >> 4, h = bh & 15;

    __shared__ float Ls[64 * 65];        // [row][col] = [c][t or s]
    const float* src = qkv + (long)b * 6291456
        + ((long)(tpe * 1024 + h * 64)) * TSEQ + tt * 64;
    #pragma unroll
    for (int ch = 0; ch < 4; ++ch) {
        int idx = tid + ch * 256;
        int c = idx >> 4, tch = idx & 15;
        float4 v = *(const float4*)(src + (long)c * TSEQ + tch * 4);
        float* L = &Ls[c * 65 + tch * 4];
        L[0] = v.x; L[1] = v.y; L[2] = v.z; L[3] = v.w;
    }
    __syncthreads();

    if (tpe == 0) {
        // Q -> [t][c], scaled
        short* dst = ws + QT_OFF + ((long)bh * TSEQ + tt * 64) * 64;
        #pragma unroll
        for (int ch = 0; ch < 2; ++ch) {
            int idx = tid + ch * 256;
            int t = idx >> 3, cch = idx & 7;
            bf16x8 o;
            #pragma unroll
            for (int j = 0; j < 8; ++j)
                o[j] = f2bf(Ls[(cch * 8 + j) * 65 + t] * SM_SCALE);
            *(bf16x8*)(dst + (long)t * 64 + cch * 8) = o;
        }
    } else if (tpe == 1) {
        // K 32x32-frag-major: f = st*4+kk, lane:
        //   K[s = tt*64 + st*32 + (lane&31)][c = kk*16 + (lane>>5)*8 + j]
        short* dst = ws + KF_OFF + (long)(bh * 32 + tt) * 4096;
        #pragma unroll
        for (int ch = 0; ch < 2; ++ch) {
            int u = tid + ch * 256;             // 0..511
            int f = u >> 6, lane = u & 63;
            int st = f >> 2, kk = f & 3;
            int l31 = lane & 31, H = lane >> 5;
            bf16x8 o;
            #pragma unroll
            for (int j = 0; j < 8; ++j)
                o[j] = f2bf(Ls[(kk * 16 + H * 8 + j) * 65 + st * 32 + l31]);
            *(bf16x8*)(dst + f * 512 + lane * 8) = o;
        }
    } else {
        // V 32x32-frag-major: f = ct*4+kk, lane:
        //   V[c = ct*32 + (lane&31)][s = tt*64 + kk*16 + (lane>>5)*8 + j]
        short* dst = ws + VF_OFF + (long)(bh * 32 + tt) * 4096;
        #pragma unroll
        for (int ch = 0; ch < 2; ++ch) {
            int u = tid + ch * 256;             // 0..511
            int f = u >> 6, lane = u & 63;
            int ct = f >> 2, kk = f & 3;
            int l31 = lane & 31, H = lane >> 5;
            bf16x8 o;
            #pragma unroll
            for (int j = 0; j < 8; ++j)
                o[j] = f2bf(Ls[(ct * 32 + l31) * 65 + kk * 16 + H * 8 + j]);
            *(bf16x8*)(dst + f * 512 + lane * 8) = o;
        }
    }
}

// load the 4 K A-frags of subtile ss (4 coalesced 1KB wave loads)
__device__ __forceinline__ void load_k(const short* KF, int ss, bf16x8 (&kc)[4]) {
    const short* kp = KF + ss * 2048;
    #pragma unroll
    for (int kk = 0; kk < 4; ++kk)
        kc[kk] = *(const bf16x8*)(kp + kk * 512);
}

// load the 4 V B-frags of subtile ss (4 coalesced 1KB wave loads)
__device__ __forceinline__ void load_v(const short* VF, int ss, bf16x8 (&vf)[4]) {
    const short* vp = VF + (ss >> 1) * 4096 + (ss & 1) * 1024;
    #pragma unroll
    for (int ct = 0; ct < 2; ++ct)
        #pragma unroll
        for (int m = 0; m < 2; ++m)
            vf[ct * 2 + m] = *(const bf16x8*)(vp + ct * 2048 + m * 512);
}

// one 32-s subtile step (kc/vf prefetched by caller): S = K Q^T (zero C-init),
// post-exp flag mask, in-register softmax -> pa, O += P V^T
__device__ __forceinline__ void step(
    int ss, const float* mfl, int H, bool qm,
    const bf16x8 (&kc)[4], const bf16x8 (&vf)[4], const bf16x8 (&qb)[4],
    f32x16 (&Oacc)[2], float &l_s)
{
    // S^T = K Q^T, zero C-init (no LDS read gating the MFMA chain)
    f32x16 Sacc;
    #pragma unroll
    for (int r = 0; r < 16; ++r) Sacc[r] = 0.0f;
    __builtin_amdgcn_s_setprio(1);
    #pragma unroll
    for (int kk = 0; kk < 4; ++kk)
        Sacc = __builtin_amdgcn_mfma_f32_32x32x16_bf16(
            kc[kk], qb[kk], Sacc, 0, 0, 0);
    __builtin_amdgcn_s_setprio(0);

    // mask flags (1.0 valid / 0.0 masked): read AFTER MFMA issue; reg r ->
    // s-local = (r&3)+8*(r>>2)+4H, same mapping as old bias. Covered by exp chain.
    f32x4 fl[4];
    #pragma unroll
    for (int g = 0; g < 4; ++g)
        fl[g] = *(const f32x4*)&mfl[ss * 32 + g * 8 + H * 4];

    // fixed-max softmax, in-register; pack to PV A-frags via
    // cvt_pk + permlane32_swap (lane l <-> l+32 complementary s-halves)
    float ls = 0.0f;
    #pragma unroll
    for (int g = 0; g < 4; ++g)
        #pragma unroll
        for (int i = 0; i < 4; ++i) {
            float e = EXPFN(Sacc[4 * g + i]) * fl[g][i];
            float pv = qm ? 1.0f : e;
            ls += pv;
            Sacc[4 * g + i] = pv;
        }
    l_s += ls;
    unsigned w0[4], w1[4];   // w?[q]: s' = q*8 + 4H + {0,1}/{2,3}
    #pragma unroll
    for (int q = 0; q < 4; ++q) {
        w0[q] = cvtpk(Sacc[4 * q + 0], Sacc[4 * q + 1]);
        w1[q] = cvtpk(Sacc[4 * q + 2], Sacc[4 * q + 3]);
    }
    bf16x8 pa[2];
    #pragma unroll
    for (int kl = 0; kl < 2; ++kl) {
        unsigned a0 = w0[kl * 2], b0 = w0[kl * 2 + 1];
        unsigned a1 = w1[kl * 2], b1 = w1[kl * 2 + 1];
        pl32swap(a0, b0);
        pl32swap(a1, b1);
        union { unsigned u[4]; bf16x8 v; } cv;
        cv.u[0] = a0; cv.u[1] = a1; cv.u[2] = b0; cv.u[3] = b1;
        pa[kl] = cv.v;   // s-local = kl*16 + H*8 + {0..7}
    }

    // O += P V^T  (D[t][c]: col=lane&31=c)
    __builtin_amdgcn_s_setprio(1);
    #pragma unroll
    for (int ct = 0; ct < 2; ++ct)
        #pragma unroll
        for (int m = 0; m < 2; ++m)
            Oacc[ct] = __builtin_amdgcn_mfma_f32_32x32x16_bf16(
                pa[m], vf[ct * 2 + m], Oacc[ct], 0, 0, 0);
    __builtin_amdgcn_s_setprio(0);
}

// ---------------- main attention (64 q/block, 4 waves = 2q x 2s, K+V pipelined) ----------------
__global__ __launch_bounds__(256, 3) void attn_kernel(
    const short* __restrict__ wsp, const int* __restrict__ mask,
    float* __restrict__ out)
{
    __shared__ __align__(16) char smem[17920];
    float* mfl = (float*)smem;               // loop: 8KB flags (1.0 valid / 0.0 masked)
    float* Os  = (float*)smem;               // epilogue: [64][68] f32 (mfl dead)
    float* Lc  = (float*)(smem + 17408);     // 128 f32 l-combine

    const int tid  = threadIdx.x;
    const int lane = tid & 63, wid = tid >> 6;      // wid 0..3
    const int l31  = lane & 31, H = lane >> 5;
    const int wq   = wid & 1,  wss = wid >> 1;      // q-subtile / s-half

    const int blk  = blockIdx.x;             // 0..1023
    const int head = blk & 31;               // same-head blocks -> same XCD
    const int qt   = blk >> 5;               // 0..31
    const int b    = head >> 4, h = head & 15;
    const int t0   = qt * 64;
    const int tw   = t0 + wq * 32;           // this wave's 32 q-rows

    const short* QT = wsp + QT_OFF + (long)head * 131072;   // [t][c]
    const short* KF = wsp + KF_OFF + (long)head * 131072 + lane * 8;
    const short* VF = wsp + VF_OFF + (long)head * 131072 + lane * 8;
    const long obase = ((long)b * 1024 + h * 64) * TSEQ;

    for (int i = tid; i < TSEQ; i += 256)
        mfl[i] = (mask[b * TSEQ + i] != 0) ? 1.0f : 0.0f;
    __syncthreads();

    // Q B-frags: qb[kk]: t = tw+l31, c = kk*16 + H*8 + j
    bf16x8 qb[4];
    #pragma unroll
    for (int kk = 0; kk < 4; ++kk)
        qb[kk] = *(const bf16x8*)(QT + (long)(tw + l31) * 64 + kk * 16 + H * 8);
    const bool qm = (mfl[tw + l31] == 0.0f);     // q-row masked -> uniform P=1

    float l_s = 0.0f;
    f32x16 Oacc[2];
    #pragma unroll
    for (int ct = 0; ct < 2; ++ct)
        #pragma unroll
        for (int r = 0; r < 16; ++r) Oacc[ct][r] = 0.0f;

    // wave processes subtiles ss = wss + 2*j, j = 0..31.
    // 1-deep K+V pipeline, static A/B buffers: frags(j+1) issued before step(j).
    bf16x8 kcA[4], kcB[4], vfA[4], vfB[4];
    load_k(KF, wss, kcA);  load_v(VF, wss, vfA);          // j = 0
    for (int jj = 0; jj < 15; ++jj) {
        const int jA = 2 * jj, jB = 2 * jj + 1;
        load_k(KF, wss + 2 * jB, kcB);                    // j = jB
        load_v(VF, wss + 2 * jB, vfB);
        step(wss + 2 * jA, mfl, H, qm, kcA, vfA, qb, Oacc, l_s);
        load_k(KF, wss + 2 * (jB + 1), kcA);              // j = jB+1
        load_v(VF, wss + 2 * (jB + 1), vfA);
        step(wss + 2 * jB, mfl, H, qm, kcB, vfB, qb, Oacc, l_s);
    }
    load_k(KF, wss + 2 * 31, kcB);                        // j = 31
    load_v(VF, wss + 2 * 31, vfB);
    step(wss + 2 * 30, mfl, H, qm, kcA, vfA, qb, Oacc, l_s);
    step(wss + 2 * 31, mfl, H, qm, kcB, vfB, qb, Oacc, l_s);

    // ---- epilogue: combine lane-halves + s-halves, scale, store ----
    __syncthreads();                         // loop done; mfl dead
    l_s += __shfl_xor(l_s, 32);              // full row sum for t = tw + l31
    if (lane < 32) Lc[wid * 32 + l31] = l_s;
    __syncthreads();
    const float inv = 1.0f / (l_s + Lc[(wid ^ 2) * 32 + l31]);
    float iw[16];
    #pragma unroll
    for (int r = 0; r < 16; ++r)
        iw[r] = __shfl(inv, (r & 3) + 8 * (r >> 2) + 4 * H);

    if (wss == 0) {
        #pragma unroll
        for (int ct = 0; ct < 2; ++ct) {
            const int c = ct * 32 + l31;
            #pragma unroll
            for (int g = 0; g < 4; ++g) {
                float4 o;
                o.x = Oacc[ct][4 * g + 0] * iw[4 * g + 0];
                o.y = Oacc[ct][4 * g + 1] * iw[4 * g + 1];
                o.z = Oacc[ct][4 * g + 2] * iw[4 * g + 2];
                o.w = Oacc[ct][4 * g + 3] * iw[4 * g + 3];
                *(float4*)&Os[c * 68 + wq * 32 + g * 8 + H * 4] = o;
            }
        }
    }
    __syncthreads();
    if (wss == 1) {
        #pragma unroll
        for (int ct = 0; ct < 2; ++ct) {
            const int c = ct * 32 + l31;
            #pragma unroll
            for (int g = 0; g < 4; ++g) {
                float* p = &Os[c * 68 + wq * 32 + g * 8 + H * 4];
                p[0] += Oacc[ct][4 * g + 0] * iw[4 * g + 0];
                p[1] += Oacc[ct][4 * g + 1] * iw[4 * g + 1];
                p[2] += Oacc[ct][4 * g + 2] * iw[4 * g + 2];
                p[3] += Oacc[ct][4 * g + 3] * iw[4 * g + 3];
            }
        }
    }
    __syncthreads();
    #pragma unroll
    for (int ch = 0; ch < 4; ++ch) {
        int idx = tid + ch * 256;           // 0..1023
        int c = idx >> 4, tch = idx & 15;
        *(float4*)(out + obase + (long)c * TSEQ + t0 + tch * 4) =
            *(const float4*)&Os[c * 68 + tch * 4];
    }
}

extern "C" void kernel_launch(void* const* d_in, const int* in_sizes, int n_in,
                              void* d_out, int out_size, void* d_ws, size_t ws_size,
                              hipStream_t stream) {
    const float* qkv  = (const float*)d_in[0];
    const int*   mask = (const int*)d_in[1];
    float*       out  = (float*)d_out;
    short*       ws   = (short*)d_ws;       // needs 24 MiB
    prep_kernel<<<dim3(3072), dim3(256), 0, stream>>>(qkv, ws);
    attn_kernel<<<dim3(1024), dim3(256), 0, stream>>>(ws, mask, out);
}

// Round 11
// 130.207 us; speedup vs baseline: 1.0501x; 1.0501x over previous
//
#include <hip/hip_runtime.h>
#include <float.h>

// QKV attention, qkv [2,3072,2048] f32, mask [2,1,2048] i32, out [2,1024,2048] f32.
// R11 = R10 with the masked-q-row boolean FIXED (R10 inverted it: valid rows
// took the uniform-P path -> absmax 0.53; everything else audited clean).
// Structure: kill the K/V L2 redundancy. Budget from R8 counters: MFMA floor
// 13.8us (MfmaUtil 26% x 52.2 = 13.6 ✓); K/V register-load traffic was 4MB/CU
// = ~31us of per-CU L2 delivery at 56B/cyc -- 60% of the kernel.
// Restructure: 128 q/block (4 waves x 32q, NO s-split -- all waves share the
// same 32-s subtile), grid 512 (2 blocks/CU), K/V staged ONCE per block into
// a 16KB LDS dbuf via global_load_lds, consumed by contiguous ds_read_b128.
// Traffic 4MB -> 1MB/CU. No s-split => no cross-wave l/O combine epilogue;
// direct global stores. One barrier/step, static A/B buffers.
// Step body = R8's proven one (bias C-init). Math: 32x32x16 MFMA, swapped QK,
// in-register softmax via v_cvt_pk_bf16_f32 + v_permlane32_swap_b32,
// fixed-max exp2. Prep unchanged.

typedef __attribute__((ext_vector_type(8))) short bf16x8;
typedef __attribute__((ext_vector_type(4))) float f32x4;
typedef __attribute__((ext_vector_type(16))) float f32x16;

#define TSEQ 2048
#define QT_OFF 0L
#define KF_OFF 4194304L
#define VF_OFF 8388608L

#if __has_builtin(__builtin_amdgcn_exp2f)
#define EXPFN(x) __builtin_amdgcn_exp2f(x)
#define SM_SCALE (0.125f * 1.44269504088896f)
#else
#define EXPFN(x) __expf(x)
#define SM_SCALE 0.125f
#endif

// async global->LDS, 16B per lane; LDS dest is wave-uniform base + lane*16
#define GLOAD16(g, l) __builtin_amdgcn_global_load_lds( \
    (const __attribute__((address_space(1))) void*)(g), \
    (__attribute__((address_space(3))) void*)(l), 16, 0, 0)

__device__ inline short f2bf(float x) {
    union { float f; unsigned u; } un; un.f = x;
    unsigned r = un.u + 0x7fffu + ((un.u >> 16) & 1u);  // RNE
    return (short)(r >> 16);
}

// pack two f32 -> [bf16(lo) | bf16(hi)<<16], single HW op
__device__ inline unsigned cvtpk(float lo, float hi) {
    unsigned r;
    asm("v_cvt_pk_bf16_f32 %0, %1, %2" : "=v"(r) : "v"(lo), "v"(hi));
    return r;
}

// swap a's lanes 32-63 with b's lanes 0-31 (register-only cross-half exchange)
__device__ inline void pl32swap(unsigned &a, unsigned &b) {
    asm volatile("v_permlane32_swap_b32 %0, %1" : "+v"(a), "+v"(b));
}

// ---------------- pre-pass: convert + reorder ----------------
// 3072 blocks: tpe = job>>10 (0=Q,1=K,2=V), 1024 each: bh = 0..31, tt = 0..31.
// All types share one coalesced 64x64 f32 tile load into padded LDS.
__global__ __launch_bounds__(256) void prep_kernel(
    const float* __restrict__ qkv, short* __restrict__ ws)
{
    const int tid = threadIdx.x;
    const int job = blockIdx.x;
    const int tpe  = job >> 10;          // 0=Q 1=K 2=V
    const int rest = job & 1023;
    const int bh = rest & 31, tt = rest >> 5;
    const int b = bh >> 4, h = bh & 15;

    __shared__ float Ls[64 * 65];        // [row][col] = [c][t or s]
    const float* src = qkv + (long)b * 6291456
        + ((long)(tpe * 1024 + h * 64)) * TSEQ + tt * 64;
    #pragma unroll
    for (int ch = 0; ch < 4; ++ch) {
        int idx = tid + ch * 256;
        int c = idx >> 4, tch = idx & 15;
        float4 v = *(const float4*)(src + (long)c * TSEQ + tch * 4);
        float* L = &Ls[c * 65 + tch * 4];
        L[0] = v.x; L[1] = v.y; L[2] = v.z; L[3] = v.w;
    }
    __syncthreads();

    if (tpe == 0) {
        // Q -> [t][c], scaled
        short* dst = ws + QT_OFF + ((long)bh * TSEQ + tt * 64) * 64;
        #pragma unroll
        for (int ch = 0; ch < 2; ++ch) {
            int idx = tid + ch * 256;
            int t = idx >> 3, cch = idx & 7;
            bf16x8 o;
            #pragma unroll
            for (int j = 0; j < 8; ++j)
                o[j] = f2bf(Ls[(cch * 8 + j) * 65 + t] * SM_SCALE);
            *(bf16x8*)(dst + (long)t * 64 + cch * 8) = o;
        }
    } else if (tpe == 1) {
        // K 32x32-frag-major: f = st*4+kk, lane:
        //   K[s = tt*64 + st*32 + (lane&31)][c = kk*16 + (lane>>5)*8 + j]
        short* dst = ws + KF_OFF + (long)(bh * 32 + tt) * 4096;
        #pragma unroll
        for (int ch = 0; ch < 2; ++ch) {
            int u = tid + ch * 256;             // 0..511
            int f = u >> 6, lane = u & 63;
            int st = f >> 2, kk = f & 3;
            int l31 = lane & 31, H = lane >> 5;
            bf16x8 o;
            #pragma unroll
            for (int j = 0; j < 8; ++j)
                o[j] = f2bf(Ls[(kk * 16 + H * 8 + j) * 65 + st * 32 + l31]);
            *(bf16x8*)(dst + f * 512 + lane * 8) = o;
        }
    } else {
        // V 32x32-frag-major: f = ct*4+kk, lane:
        //   V[c = ct*32 + (lane&31)][s = tt*64 + kk*16 + (lane>>5)*8 + j]
        short* dst = ws + VF_OFF + (long)(bh * 32 + tt) * 4096;
        #pragma unroll
        for (int ch = 0; ch < 2; ++ch) {
            int u = tid + ch * 256;             // 0..511
            int f = u >> 6, lane = u & 63;
            int ct = f >> 2, kk = f & 3;
            int l31 = lane & 31, H = lane >> 5;
            bf16x8 o;
            #pragma unroll
            for (int j = 0; j < 8; ++j)
                o[j] = f2bf(Ls[(ct * 32 + l31) * 65 + kk * 16 + H * 8 + j]);
            *(bf16x8*)(dst + f * 512 + lane * 8) = o;
        }
    }
}

// stage 32-s subtile j into LDS buffer (K 4KB + V 4KB); each wave issues 2
// global_load_lds of 1KB. K subtile j = frag bytes j*4096..+4096 (contiguous).
// V subtile j = frags {ct*4 + 2*(j&1) + kv}: chunk w=ct*2+kv from
// (j>>1)*8192 + ct*4096 + (j&1)*2048 + kv*1024.
__device__ __forceinline__ void stageKV(
    const char* KFb, const char* VFb, int j, char* kdst, char* vdst,
    int wid, int lane)
{
    GLOAD16(KFb + (long)j * 4096 + wid * 1024 + lane * 16, kdst + wid * 1024);
    const long voff = (long)(j >> 1) * 8192
        + (wid >> 1) * 4096 + (j & 1) * 2048 + (wid & 1) * 1024;
    GLOAD16(VFb + voff + lane * 16, vdst + wid * 1024);
}

// one 32-s step from LDS buffer: S = K Q^T + bias(C-init), in-register
// softmax -> pa (cvt_pk + permlane32_swap), O += P V^T
__device__ __forceinline__ void computeStep(
    int j, const short* kb, const short* vb, const float* mbf,
    int H, int lane, bool qm,
    const bf16x8 (&qb)[4], f32x16 (&Oacc)[2], float &l_s)
{
    // K A-frags: contiguous conflict-free ds_read_b128
    bf16x8 kc[4];
    #pragma unroll
    for (int kk = 0; kk < 4; ++kk)
        kc[kk] = *(const bf16x8*)(kb + kk * 512 + lane * 8);

    // bias C-init: reg r -> s-local = (r&3)+8*(r>>2)+4H; broadcast b128 reads
    f32x16 Sacc;
    #pragma unroll
    for (int g = 0; g < 4; ++g) {
        f32x4 b4 = *(const f32x4*)&mbf[j * 32 + g * 8 + H * 4];
        Sacc[4 * g + 0] = b4[0];
        Sacc[4 * g + 1] = b4[1];
        Sacc[4 * g + 2] = b4[2];
        Sacc[4 * g + 3] = b4[3];
    }

    // S^T = K Q^T + bias  (D[s][t]: col=lane&31=t)
    __builtin_amdgcn_s_setprio(1);
    #pragma unroll
    for (int kk = 0; kk < 4; ++kk)
        Sacc = __builtin_amdgcn_mfma_f32_32x32x16_bf16(
            kc[kk], qb[kk], Sacc, 0, 0, 0);
    __builtin_amdgcn_s_setprio(0);

    // V B-frags (LDS, low latency; issued before softmax VALU)
    bf16x8 vf[4];
    #pragma unroll
    for (int w = 0; w < 4; ++w)
        vf[w] = *(const bf16x8*)(vb + w * 512 + lane * 8);

    // fixed-max softmax, in-register; pack to PV A-frags via
    // cvt_pk + permlane32_swap (lane l <-> l+32 complementary s-halves)
    float ls = 0.0f;
    #pragma unroll
    for (int r = 0; r < 16; ++r) {
        float e = EXPFN(Sacc[r]);
        float pv = qm ? 1.0f : e;
        ls += pv;
        Sacc[r] = pv;
    }
    l_s += ls;
    unsigned w0[4], w1[4];   // w?[q]: s' = q*8 + 4H + {0,1}/{2,3}
    #pragma unroll
    for (int q = 0; q < 4; ++q) {
        w0[q] = cvtpk(Sacc[4 * q + 0], Sacc[4 * q + 1]);
        w1[q] = cvtpk(Sacc[4 * q + 2], Sacc[4 * q + 3]);
    }
    bf16x8 pa[2];
    #pragma unroll
    for (int kl = 0; kl < 2; ++kl) {
        unsigned a0 = w0[kl * 2], b0 = w0[kl * 2 + 1];
        unsigned a1 = w1[kl * 2], b1 = w1[kl * 2 + 1];
        pl32swap(a0, b0);
        pl32swap(a1, b1);
        union { unsigned u[4]; bf16x8 v; } cv;
        cv.u[0] = a0; cv.u[1] = a1; cv.u[2] = b0; cv.u[3] = b1;
        pa[kl] = cv.v;   // s-local = kl*16 + H*8 + {0..7}
    }

    // O += P V^T  (D[t][c]: col=lane&31=c)
    __builtin_amdgcn_s_setprio(1);
    #pragma unroll
    for (int ct = 0; ct < 2; ++ct)
        #pragma unroll
        for (int m = 0; m < 2; ++m)
            Oacc[ct] = __builtin_amdgcn_mfma_f32_32x32x16_bf16(
                pa[m], vf[ct * 2 + m], Oacc[ct], 0, 0, 0);
    __builtin_amdgcn_s_setprio(0);
}

// ---------------- main attention (128 q/block, 4 waves share s-steps) ----------------
__global__ __launch_bounds__(256, 2) void attn_kernel(
    const short* __restrict__ wsp, const int* __restrict__ mask,
    float* __restrict__ out)
{
    __shared__ __align__(16) char smem[24576];
    // buf b at b*8192: K 4KB | V 4KB. mask bias at 16384 (8KB).
    float* mbf = (float*)(smem + 16384);

    const int tid  = threadIdx.x;
    const int lane = tid & 63, wid = tid >> 6;      // wid 0..3 = q-subtile
    const int l31  = lane & 31, H = lane >> 5;

    const int blk  = blockIdx.x;             // 0..511
    const int head = blk & 31;               // same-head blocks -> same XCD
    const int qt   = blk >> 5;               // 0..15
    const int b    = head >> 4, h = head & 15;
    const int tw   = qt * 128 + wid * 32;    // this wave's 32 q-rows

    const short* QT = wsp + QT_OFF + (long)head * 131072;            // [t][c]
    const char*  KFb = (const char*)(wsp + KF_OFF + (long)head * 131072);
    const char*  VFb = (const char*)(wsp + VF_OFF + (long)head * 131072);
    const long obase = ((long)b * 1024 + h * 64) * TSEQ;

    for (int i = tid; i < TSEQ; i += 256)
        mbf[i] = (mask[b * TSEQ + i] != 0) ? 0.0f : -1e30f;

    // stage subtile 0 into buf0 (8 x 1KB loads across 4 waves)
    stageKV(KFb, VFb, 0, smem, smem + 4096, wid, lane);
    __syncthreads();   // drains vmcnt: subtile 0 resident; mbf visible

    // Q B-frags: qb[kk]: t = tw+l31, c = kk*16 + H*8 + j
    bf16x8 qb[4];
    #pragma unroll
    for (int kk = 0; kk < 4; ++kk)
        qb[kk] = *(const bf16x8*)(QT + (long)(tw + l31) * 64 + kk * 16 + H * 8);
    // mbf: 0.0 = valid, -1e30 = masked. qm TRUE for MASKED q-row -> uniform P=1.
    // (R10 bug: this boolean was inverted.)
    const bool qm = (mbf[tw + l31] != 0.0f);

    float l_s = 0.0f;
    f32x16 Oacc[2];
    #pragma unroll
    for (int ct = 0; ct < 2; ++ct)
        #pragma unroll
        for (int r = 0; r < 16; ++r) Oacc[ct][r] = 0.0f;

    const short* kb0 = (const short*)smem;
    const short* vb0 = (const short*)(smem + 4096);
    const short* kb1 = (const short*)(smem + 8192);
    const short* vb1 = (const short*)(smem + 12288);

    // 64 subtile-steps, static A/B double-buffer, one barrier per step.
    // stage(next) issued at step top -> full step (~MFMA+softmax) to land.
    for (int jj = 0; jj < 31; ++jj) {
        const int jA = 2 * jj, jB = 2 * jj + 1;
        stageKV(KFb, VFb, jB, smem + 8192, smem + 12288, wid, lane);
        computeStep(jA, kb0, vb0, mbf, H, lane, qm, qb, Oacc, l_s);
        __syncthreads();
        stageKV(KFb, VFb, jB + 1, smem, smem + 4096, wid, lane);
        computeStep(jB, kb1, vb1, mbf, H, lane, qm, qb, Oacc, l_s);
        __syncthreads();
    }
    stageKV(KFb, VFb, 63, smem + 8192, smem + 12288, wid, lane);
    computeStep(62, kb0, vb0, mbf, H, lane, qm, qb, Oacc, l_s);
    __syncthreads();
    computeStep(63, kb1, vb1, mbf, H, lane, qm, qb, Oacc, l_s);

    // ---- epilogue: per-wave only (each wave saw ALL s) ----
    l_s += __shfl_xor(l_s, 32);              // combine lane-half partial sums
    const float inv = 1.0f / l_s;
    float iw[16];
    #pragma unroll
    for (int r = 0; r < 16; ++r)
        iw[r] = __shfl(inv, (r & 3) + 8 * (r >> 2) + 4 * H);

    // direct stores: lanes l31 and l31+32 cover complementary t-quads of the
    // same c row -> 128B per (c, wave) net; no LDS transpose needed.
    #pragma unroll
    for (int ct = 0; ct < 2; ++ct) {
        const int c = ct * 32 + l31;
        #pragma unroll
        for (int g = 0; g < 4; ++g) {
            float4 o;
            o.x = Oacc[ct][4 * g + 0] * iw[4 * g + 0];
            o.y = Oacc[ct][4 * g + 1] * iw[4 * g + 1];
            o.z = Oacc[ct][4 * g + 2] * iw[4 * g + 2];
            o.w = Oacc[ct][4 * g + 3] * iw[4 * g + 3];
            *(float4*)(out + obase + (long)c * TSEQ + tw + g * 8 + H * 4) = o;
        }
    }
}

extern "C" void kernel_launch(void* const* d_in, const int* in_sizes, int n_in,
                              void* d_out, int out_size, void* d_ws, size_t ws_size,
                              hipStream_t stream) {
    const float* qkv  = (const float*)d_in[0];
    const int*   mask = (const int*)d_in[1];
    float*       out  = (float*)d_out;
    short*       ws   = (short*)d_ws;       // needs 24 MiB
    prep_kernel<<<dim3(3072), dim3(256), 0, stream>>>(qkv, ws);
    attn_kernel<<<dim3(512), dim3(256), 0, stream>>>(ws, mask, out);
}